// Round 5
// baseline (128.072 us; speedup 1.0000x reference)
//
#include <hip/hip_runtime.h>
#include <math.h>

// B=64, T=512, C=384, H=64. fp32 in/out; bf16 MFMA internally.
#define NB 64
#define NT 512
#define NC 384
#define NH 64

typedef __attribute__((ext_vector_type(8))) short bf16x8;
typedef __attribute__((ext_vector_type(4))) float f32x4;

__device__ __forceinline__ unsigned short f2bf(float f) {
  unsigned int u = __float_as_uint(f);
  return (unsigned short)((u + 0x7FFFu + ((u >> 16) & 1u)) >> 16);
}
// packed fp32x2 -> bf16x2 (RNE), single VALU op. lo in [15:0], hi in [31:16].
__device__ __forceinline__ unsigned int cvt_pk_bf16(float lo, float hi) {
  unsigned int r;
  asm("v_cvt_pk_bf16_f32 %0, %1, %2" : "=v"(r) : "v"(lo), "v"(hi));
  return r;
}

// ---------------------------------------------------------------------------
// Kernel 0: W[384][64] fp32 x3 -> Wt[192][384] bf16 (transposed, row-major)
// ---------------------------------------------------------------------------
__global__ __launch_bounds__(256) void wtrans_kernel(
    const float* __restrict__ Wq, const float* __restrict__ Wk,
    const float* __restrict__ Wv, unsigned short* __restrict__ Wt) {
  int id = blockIdx.x * 256 + threadIdx.x;
  if (id >= 3 * NC * NH) return;
  int m = id / (NC * NH);
  int r = id % (NC * NH);
  int c = r / NH;
  int h = r % NH;
  const float* W = (m == 0) ? Wq : ((m == 1) ? Wk : Wv);
  Wt[(m * NH + h) * NC + c] = f2bf(W[c * NH + h]);
}

// ---------------------------------------------------------------------------
// Kernel 1: fused QKV projection. M=32768, K=384, N=192.
// r5: 64-row tile (grid 512 — empirically faster than r4's 32-row/1024) with
// an INTERNAL two-half software pipeline (T14 async-stage split):
//   load h0 -> cvt+LDS h0 -> barrier -> ISSUE h1 loads ->
//   K-loop h0 + epilogue h0 (h1 loads in flight) ->
//   cvt+LDS h1 (separate buffer, no extra barrier needed) -> barrier ->
//   K-loop h1 + epilogue h1.
// kc-outer loop keeps only 2 B-frags live (r4's fix for the r2 VGPR-sinking
// regression); total ~80 VGPR < the (384,3) 128-cap so the h1 prefetch has
// no pressure reason to be sunk. Wave w owns N-tiles {2w,2w+1}
// (w0-1: q, w2-3: k, w4-5: v).
// ---------------------------------------------------------------------------
#define XS 392  // 32 rows x 392 ushorts per half; 784 B row stride
__global__ __launch_bounds__(384, 3) void proj_kernel(
    const float* __restrict__ x, const unsigned short* __restrict__ Wt,
    unsigned short* __restrict__ q, unsigned short* __restrict__ k,
    unsigned short* __restrict__ vt) {
  __shared__ unsigned short xs[2][32 * XS];  // 2 x 25088 B
  const int t = threadIdx.x;  // 0..383
  const int m0 = blockIdx.x * 64;
  const int w = t / 64, l = t & 63, mi = l & 15, quad = l >> 4;

  const unsigned short* wr0 =
      Wt + (size_t)((w * 2 + 0) * 16 + mi) * NC + quad * 8;
  const unsigned short* wr1 =
      Wt + (size_t)((w * 2 + 1) * 16 + mi) * NC + quad * 8;

  float4 xr[8];
  // half0: load 32 rows x 384 fp32 (coalesced float4)
#pragma unroll
  for (int i = 0; i < 8; ++i) {
    int u = t + i * 384;  // row = u/96, 4-float seg = u%96
    xr[i] = *(const float4*)(x + (size_t)(m0 + u / 96) * NC + (u % 96) * 4);
  }
  // half0: convert + LDS write
#pragma unroll
  for (int i = 0; i < 8; ++i) {
    int u = t + i * 384;
    uint2 bbu;
    bbu.x = cvt_pk_bf16(xr[i].x, xr[i].y);
    bbu.y = cvt_pk_bf16(xr[i].z, xr[i].w);
    *(uint2*)&xs[0][(u / 96) * XS + (u % 96) * 4] = bbu;
  }
  __syncthreads();

  // half1 loads issued NOW — in flight across half0's K-loop + epilogue
#pragma unroll
  for (int i = 0; i < 8; ++i) {
    int u = t + i * 384;
    xr[i] =
        *(const float4*)(x + (size_t)(m0 + 32 + u / 96) * NC + (u % 96) * 4);
  }

// K-loop + epilogue for half HH (rows m0 + HH*32 .. +31)
#define COMPUTE_HALF(HH)                                                      \
  {                                                                           \
    f32x4 acc[2][2]; /* [ntl][ms] */                                          \
    const f32x4 zero_ = {0.f, 0.f, 0.f, 0.f};                                 \
    _Pragma("unroll") for (int i_ = 0; i_ < 2; ++i_)                          \
        _Pragma("unroll") for (int j_ = 0; j_ < 2; ++j_) acc[i_][j_] = zero_; \
    _Pragma("unroll") for (int kc_ = 0; kc_ < 12; ++kc_) {                    \
      bf16x8 b0_ = *(const bf16x8*)(wr0 + kc_ * 32);                          \
      bf16x8 b1_ = *(const bf16x8*)(wr1 + kc_ * 32);                          \
      _Pragma("unroll") for (int ms_ = 0; ms_ < 2; ++ms_) {                   \
        bf16x8 a_ = *(const bf16x8*)&xs[HH][(ms_ * 16 + mi) * XS + kc_ * 32 + \
                                           quad * 8];                         \
        acc[0][ms_] = __builtin_amdgcn_mfma_f32_16x16x32_bf16(a_, b0_,        \
                                                              acc[0][ms_],   \
                                                              0, 0, 0);       \
        acc[1][ms_] = __builtin_amdgcn_mfma_f32_16x16x32_bf16(a_, b1_,        \
                                                              acc[1][ms_],   \
                                                              0, 0, 0);       \
      }                                                                       \
    }                                                                         \
    /* epilogue: C/D layout col=mi (=n), row=quad*4+r (=m). */                \
    if (w < 4) { /* q (waves 0-1) / k (waves 2-3) */                          \
      unsigned short* dst_ = (w < 2) ? q : k;                                 \
      const float sc_ = (w < 2) ? 0.125f : 1.0f;                              \
      _Pragma("unroll") for (int ntl_ = 0; ntl_ < 2; ++ntl_) {                \
        int hcol_ = ((w * 2 + ntl_) & 3) * 16 + mi;                           \
        _Pragma("unroll") for (int ms_ = 0; ms_ < 2; ++ms_) {                 \
          unsigned int u01_ = cvt_pk_bf16(acc[ntl_][ms_][0] * sc_,            \
                                          acc[ntl_][ms_][1] * sc_);           \
          unsigned int u23_ = cvt_pk_bf16(acc[ntl_][ms_][2] * sc_,            \
                                          acc[ntl_][ms_][3] * sc_);           \
          size_t base_ =                                                      \
              (size_t)(m0 + (HH)*32 + ms_ * 16 + quad * 4) * NH + hcol_;      \
          dst_[base_] = (unsigned short)u01_;                                 \
          dst_[base_ + NH] = (unsigned short)(u01_ >> 16);                    \
          dst_[base_ + 2 * NH] = (unsigned short)u23_;                        \
          dst_[base_ + 3 * NH] = (unsigned short)(u23_ >> 16);                \
        }                                                                     \
      }                                                                       \
    } else { /* v (waves 4-5): 4 consecutive tokens per lane -> 8B store */   \
      int bb_ = m0 >> 9, t0_ = m0 & 511;                                      \
      _Pragma("unroll") for (int ntl_ = 0; ntl_ < 2; ++ntl_) {                \
        int hcol_ = ((w * 2 + ntl_) & 3) * 16 + mi;                           \
        _Pragma("unroll") for (int ms_ = 0; ms_ < 2; ++ms_) {                 \
          uint2 s_;                                                           \
          s_.x = cvt_pk_bf16(acc[ntl_][ms_][0], acc[ntl_][ms_][1]);           \
          s_.y = cvt_pk_bf16(acc[ntl_][ms_][2], acc[ntl_][ms_][3]);           \
          *(uint2*)&vt[((size_t)bb_ * NH + hcol_) * NT + t0_ + (HH)*32 +      \
                       ms_ * 16 + quad * 4] = s_;                             \
        }                                                                     \
      }                                                                       \
    }                                                                         \
  }

  COMPUTE_HALF(0)

  // half1: convert + LDS write (separate buffer -> no barrier needed before)
#pragma unroll
  for (int i = 0; i < 8; ++i) {
    int u = t + i * 384;
    uint2 bbu;
    bbu.x = cvt_pk_bf16(xr[i].x, xr[i].y);
    bbu.y = cvt_pk_bf16(xr[i].z, xr[i].w);
    *(uint2*)&xs[1][(u / 96) * XS + (u % 96) * 4] = bbu;
  }
  __syncthreads();

  COMPUTE_HALF(1)
#undef COMPUTE_HALF
}

// ---------------------------------------------------------------------------
// Kernel 2: causal flash attention. ONE WAVE per (b, 16-row q-tile).
// Register double-buffered K/V tiles (next tile's 16 loads in flight during
// current tile's softmax+PV); alpha / inv broadcast via wave-local LDS;
// P-pack via v_cvt_pk_bf16_f32. Zero barriers throughout.
// ---------------------------------------------------------------------------
#define PSTR 72
__global__ __launch_bounds__(64, 2) void attn_kernel(
    const unsigned short* __restrict__ q, const unsigned short* __restrict__ k,
    const unsigned short* __restrict__ vt, float* __restrict__ out) {
  __shared__ unsigned short ps[16 * PSTR];
  __shared__ __align__(16) float alpha_s[16];
  const int l = threadIdx.x;
  const int mi = l & 15, quad = l >> 4;
  const int bx = blockIdx.x;
  const int qi = 31 - (bx >> 6);  // heavy tiles first
  const int b = bx & 63;

  const unsigned short* qrow = q + ((size_t)b * NT + qi * 16 + mi) * NH;
  bf16x8 qb0 = *(const bf16x8*)(qrow + quad * 8);
  bf16x8 qb1 = *(const bf16x8*)(qrow + 32 + quad * 8);

  f32x4 accO[4];
  const f32x4 zero = {0.f, 0.f, 0.f, 0.f};
#pragma unroll
  for (int i = 0; i < 4; ++i) accO[i] = zero;
  float mrow = -INFINITY, lrow = 0.f;  // per-lane q-row = qi*16 + mi

  const unsigned short* kbase = k + (size_t)b * NT * NH;
  const unsigned short* vbase = vt + (size_t)b * NH * NT;
  const int ktmax = (qi * 16 + 15) >> 6;

  bf16x8 ka0A[4], ka1A[4], va0A[4], va1A[4];  // ping
  bf16x8 ka0B[4], ka1B[4], va0B[4], va1B[4];  // pong

#define LOADKV(KA0, KA1, VA0, VA1, KT)                                        \
  {                                                                           \
    const unsigned short* kb_ = kbase + (size_t)(KT) * 64 * NH;               \
    const unsigned short* vb_ = vbase + (KT) * 64;                            \
    _Pragma("unroll") for (int nt_ = 0; nt_ < 4; ++nt_) {                     \
      const unsigned short* kr_ =                                             \
          kb_ + (size_t)(nt_ * 16 + mi) * NH + quad * 8;                      \
      KA0[nt_] = *(const bf16x8*)kr_;                                         \
      KA1[nt_] = *(const bf16x8*)(kr_ + 32);                                  \
      const unsigned short* vr_ =                                             \
          vb_ + (size_t)(nt_ * 16 + mi) * NT + quad * 8;                      \
      VA0[nt_] = *(const bf16x8*)vr_;                                         \
      VA1[nt_] = *(const bf16x8*)(vr_ + 32);                                  \
    }                                                                         \
  }

#define COMPUTE(KA0, KA1, VA0, VA1, KT)                                       \
  {                                                                           \
    /* S^T tile: A = K rows (m=key), B = Q rows (n=q). */                     \
    float p_[4][4];                                                           \
    _Pragma("unroll") for (int nt_ = 0; nt_ < 4; ++nt_) {                     \
      f32x4 z_ = zero;                                                        \
      z_ = __builtin_amdgcn_mfma_f32_16x16x32_bf16(KA0[nt_], qb0, z_, 0, 0, 0); \
      z_ = __builtin_amdgcn_mfma_f32_16x16x32_bf16(KA1[nt_], qb1, z_, 0, 0, 0); \
      _Pragma("unroll") for (int r_ = 0; r_ < 4; ++r_) p_[nt_][r_] = z_[r_];  \
    }                                                                         \
    if ((KT) == ktmax) { /* causal mask on diagonal tile */                   \
      _Pragma("unroll") for (int nt_ = 0; nt_ < 4; ++nt_)                     \
          _Pragma("unroll") for (int r_ = 0; r_ < 4; ++r_)                    \
              if ((KT)*64 + nt_ * 16 + quad * 4 + r_ > qi * 16 + mi)          \
        p_[nt_][r_] = -INFINITY;                                              \
    }                                                                         \
    float vmax_ = -INFINITY;                                                  \
    _Pragma("unroll") for (int nt_ = 0; nt_ < 4; ++nt_)                       \
        _Pragma("unroll") for (int r_ = 0; r_ < 4; ++r_)                      \
            vmax_ = fmaxf(vmax_, p_[nt_][r_]);                                \
    vmax_ = fmaxf(vmax_, __shfl_xor(vmax_, 16));                              \
    vmax_ = fmaxf(vmax_, __shfl_xor(vmax_, 32));                              \
    float mn_ = fmaxf(mrow, vmax_);                                           \
    float alpha_ = __expf(mrow - mn_);                                        \
    mrow = mn_;                                                               \
    float rsum_ = 0.f;                                                        \
    _Pragma("unroll") for (int nt_ = 0; nt_ < 4; ++nt_)                       \
        _Pragma("unroll") for (int r_ = 0; r_ < 4; ++r_) {                    \
      p_[nt_][r_] = __expf(p_[nt_][r_] - mn_);                                \
      rsum_ += p_[nt_][r_];                                                   \
    }                                                                         \
    rsum_ += __shfl_xor(rsum_, 16);                                           \
    rsum_ += __shfl_xor(rsum_, 32);                                           \
    lrow = lrow * alpha_ + rsum_;                                             \
    /* alpha broadcast + P -> LDS (wave-local, no barrier) */                 \
    if (quad == 0) alpha_s[mi] = alpha_;                                      \
    _Pragma("unroll") for (int nt_ = 0; nt_ < 4; ++nt_) {                     \
      uint2 pk_;                                                              \
      pk_.x = cvt_pk_bf16(p_[nt_][0], p_[nt_][1]);                            \
      pk_.y = cvt_pk_bf16(p_[nt_][2], p_[nt_][3]);                            \
      *(uint2*)&ps[mi * PSTR + nt_ * 16 + quad * 4] = pk_;                    \
    }                                                                         \
    bf16x8 pa0_ = *(const bf16x8*)&ps[mi * PSTR + quad * 8];                  \
    bf16x8 pa1_ = *(const bf16x8*)&ps[mi * PSTR + 32 + quad * 8];             \
    f32x4 av_ = *(const f32x4*)&alpha_s[quad * 4];                            \
    _Pragma("unroll") for (int hi_ = 0; hi_ < 4; ++hi_)                       \
        _Pragma("unroll") for (int r_ = 0; r_ < 4; ++r_)                      \
            accO[hi_][r_] *= av_[r_];                                         \
    /* O += P V  (A = P rows, B = V^T rows; D col=h, row=q) */                \
    _Pragma("unroll") for (int hi_ = 0; hi_ < 4; ++hi_) {                     \
      accO[hi_] = __builtin_amdgcn_mfma_f32_16x16x32_bf16(pa0_, VA0[hi_],     \
                                                          accO[hi_], 0, 0, 0); \
      accO[hi_] = __builtin_amdgcn_mfma_f32_16x16x32_bf16(pa1_, VA1[hi_],     \
                                                          accO[hi_], 0, 0, 0); \
    }                                                                         \
  }

  // software-pipelined main loop: tile kt+1's loads in flight during tile
  // kt's softmax+PV. Ping-pong register sets; all indices compile-time.
  LOADKV(ka0A, ka1A, va0A, va1A, 0);
  int kt = 0;
  while (kt < ktmax) {
    LOADKV(ka0B, ka1B, va0B, va1B, kt + 1);
    COMPUTE(ka0A, ka1A, va0A, va1A, kt);
    ++kt;
    if (kt < ktmax) {
      LOADKV(ka0A, ka1A, va0A, va1A, kt + 1);
      COMPUTE(ka0B, ka1B, va0B, va1B, kt);
      ++kt;
    } else {
      COMPUTE(ka0B, ka1B, va0B, va1B, kt);
      ++kt;
    }
  }
  if (kt == ktmax) COMPUTE(ka0A, ka1A, va0A, va1A, kt);

  // epilogue: inv broadcast via LDS (ordered after last COMPUTE's alpha use)
  float inv = 1.f / lrow;
  if (quad == 0) alpha_s[mi] = inv;
  f32x4 iv4 = *(const f32x4*)&alpha_s[quad * 4];
  const size_t obase = ((size_t)b * NT + qi * 16) * NH;
#pragma unroll
  for (int r = 0; r < 4; ++r) {
#pragma unroll
    for (int hi = 0; hi < 4; ++hi)
      out[obase + (size_t)(quad * 4 + r) * NH + hi * 16 + mi] =
          accO[hi][r] * iv4[r];
  }
#undef LOADKV
#undef COMPUTE
}

extern "C" void kernel_launch(void* const* d_in, const int* in_sizes, int n_in,
                              void* d_out, int out_size, void* d_ws, size_t ws_size,
                              hipStream_t stream) {
  const float* x  = (const float*)d_in[0];
  const float* Wq = (const float*)d_in[1];
  const float* Wk = (const float*)d_in[2];
  const float* Wv = (const float*)d_in[3];

  unsigned short* Wt = (unsigned short*)d_ws;          // 192*384
  unsigned short* qb = Wt + 192 * 384;                 // 32768*64 each
  unsigned short* kb = qb + 32768 * 64;
  unsigned short* vtb = kb + 32768 * 64;               // Vt[b][h][t]
  float* out = (float*)d_out;

  wtrans_kernel<<<288, 256, 0, stream>>>(Wq, Wk, Wv, Wt);
  proj_kernel<<<512, 384, 0, stream>>>(x, Wt, qb, kb, vtb);
  attn_kernel<<<2048, 64, 0, stream>>>(qb, kb, vtb, out);
}

// Round 6
// 121.835 us; speedup vs baseline: 1.0512x; 1.0512x over previous
//
#include <hip/hip_runtime.h>
#include <math.h>

// B=64, T=512, C=384, H=64. fp32 in/out; bf16 MFMA internally.
// REVERT to the r0 kernel (best measured: 120.9 us this session, 121.9 prior).
// Rounds 2-5 tested three proj redesigns (fused-W, 32-row/kc-outer,
// two-half pipeline): all regressed 3-18 us. The timed region is
// ~84-88 us of harness workspace poison-fills (2 x 256 MiB at ~80% HBM peak)
// plus ~35 us of kernels; this structure is the empirical floor.
#define NB 64
#define NT 512
#define NC 384
#define NH 64

typedef __attribute__((ext_vector_type(8))) short bf16x8;
typedef __attribute__((ext_vector_type(4))) float f32x4;

__device__ __forceinline__ unsigned short f2bf(float f) {
  unsigned int u = __float_as_uint(f);
  return (unsigned short)((u + 0x7FFFu + ((u >> 16) & 1u)) >> 16);
}
__device__ __forceinline__ unsigned int pk2bf(float a, float b) {
  return (unsigned int)f2bf(a) | ((unsigned int)f2bf(b) << 16);
}

// ---------------------------------------------------------------------------
// Kernel 0: W[384][64] fp32 x3 -> Wt[192][384] bf16 (transposed, row-major)
// ---------------------------------------------------------------------------
__global__ __launch_bounds__(256) void wtrans_kernel(
    const float* __restrict__ Wq, const float* __restrict__ Wk,
    const float* __restrict__ Wv, unsigned short* __restrict__ Wt) {
  int id = blockIdx.x * 256 + threadIdx.x;
  if (id >= 3 * NC * NH) return;
  int m = id / (NC * NH);
  int r = id % (NC * NH);
  int c = r / NH;
  int h = r % NH;
  const float* W = (m == 0) ? Wq : ((m == 1) ? Wk : Wv);
  Wt[(m * NH + h) * NC + c] = f2bf(W[c * NH + h]);
}

// ---------------------------------------------------------------------------
// Kernel 1: fused QKV projection. M=32768, K=384, N=192.
// 384 threads = 6 waves; wave w owns N-tiles {2w, 2w+1} (w0-1: q, w2-3: k,
// w4-5: v). Its 24 B-frags (96 VGPR) load from L2 once, latency hidden by
// the single staging barrier. K-loop = LDS A-frag reads + MFMA only.
// ONE barrier total; no LDS reuse; V stored directly from C-layout as
// contiguous ushort4 (4 tokens) into vt[b][h][t]. q scaled by 0.125 (exact).
// ---------------------------------------------------------------------------
#define XS 392  // 64 rows x 392 ushorts; 784 B row stride
__global__ __launch_bounds__(384, 3) void proj_kernel(
    const float* __restrict__ x, const unsigned short* __restrict__ Wt,
    unsigned short* __restrict__ q, unsigned short* __restrict__ k,
    unsigned short* __restrict__ vt) {
  __shared__ unsigned short xs[64 * XS];  // 50176 B
  const int t = threadIdx.x;  // 0..383
  const int m0 = blockIdx.x * 64;
  const int w = t / 64, l = t & 63, mi = l & 15, quad = l >> 4;

  // stage x tile: 64 rows x 384 fp32 -> bf16 (coalesced float4)
#pragma unroll 4
  for (int i = 0; i < 16; ++i) {
    int u = t + i * 384;  // 0..6143; row = u/96, 4-float seg = u%96
    int row = u / 96;
    int cp = (u % 96) * 4;
    float4 a = *(const float4*)(x + (size_t)(m0 + row) * NC + cp);
    ushort4 bb;
    bb.x = f2bf(a.x); bb.y = f2bf(a.y); bb.z = f2bf(a.z); bb.w = f2bf(a.w);
    *(ushort4*)&xs[row * XS + cp] = bb;
  }

  // wave-resident B-frags: tiles 2w, 2w+1 (issued before the barrier so L2
  // latency overlaps other waves' staging)
  bf16x8 bfr[2][12];
#pragma unroll
  for (int ntl = 0; ntl < 2; ++ntl) {
    const unsigned short* wr =
        Wt + (size_t)((w * 2 + ntl) * 16 + mi) * NC + quad * 8;
#pragma unroll
    for (int kc = 0; kc < 12; ++kc)
      bfr[ntl][kc] = *(const bf16x8*)(wr + kc * 32);
  }
  __syncthreads();

  f32x4 acc[2][4];  // [ntl][msub]
  const f32x4 zero = {0.f, 0.f, 0.f, 0.f};
#pragma unroll
  for (int i = 0; i < 2; ++i)
#pragma unroll
    for (int j = 0; j < 4; ++j) acc[i][j] = zero;

#pragma unroll
  for (int msub = 0; msub < 4; ++msub) {
#pragma unroll
    for (int kc = 0; kc < 12; ++kc) {
      bf16x8 a = *(const bf16x8*)&xs[(msub * 16 + mi) * XS + kc * 32 + quad * 8];
      acc[0][msub] =
          __builtin_amdgcn_mfma_f32_16x16x32_bf16(a, bfr[0][kc], acc[0][msub], 0, 0, 0);
      acc[1][msub] =
          __builtin_amdgcn_mfma_f32_16x16x32_bf16(a, bfr[1][kc], acc[1][msub], 0, 0, 0);
    }
  }

  // epilogue (no barriers, pure global stores).
  // C/D layout: col=mi (=n within tile), row=quad*4+r (=m). Tile = 2w+ntl;
  // matrix = tile>>2 (uniform per wave), h = (tile&3)*16 + mi.
  if (w < 4) {  // q (waves 0-1) / k (waves 2-3): scalar ushort stores
    unsigned short* dst = (w < 2) ? q : k;
    const float sc = (w < 2) ? 0.125f : 1.0f;  // fold 1/sqrt(64), exact
#pragma unroll
    for (int ntl = 0; ntl < 2; ++ntl) {
      int tile = w * 2 + ntl;
      int h = (tile & 3) * 16 + mi;
#pragma unroll
      for (int msub = 0; msub < 4; ++msub)
#pragma unroll
        for (int r = 0; r < 4; ++r)
          dst[(size_t)(m0 + msub * 16 + quad * 4 + r) * NH + h] =
              f2bf(acc[ntl][msub][r] * sc);
    }
  } else {  // v (waves 4-5): 4 consecutive tokens per lane -> ushort4 store
    int bb = m0 >> 9, t0 = m0 & 511;
#pragma unroll
    for (int ntl = 0; ntl < 2; ++ntl) {
      int tile = w * 2 + ntl;
      int h = (tile & 3) * 16 + mi;
#pragma unroll
      for (int msub = 0; msub < 4; ++msub) {
        ushort4 s;
        s.x = f2bf(acc[ntl][msub][0]);
        s.y = f2bf(acc[ntl][msub][1]);
        s.z = f2bf(acc[ntl][msub][2]);
        s.w = f2bf(acc[ntl][msub][3]);
        *(ushort4*)&vt[((size_t)bb * NH + h) * NT + t0 + msub * 16 + quad * 4] = s;
      }
    }
  }
}

// ---------------------------------------------------------------------------
// Kernel 2: causal flash attention (r4 form, passed twice). ONE WAVE per
// (b, 16-row q-tile). Fragments gathered from L2-hot global, 16 loads in
// flight per k-tile; P round-trip via wave-local LDS; zero barriers.
// ---------------------------------------------------------------------------
#define PSTR 72
__global__ __launch_bounds__(64) void attn_kernel(
    const unsigned short* __restrict__ q, const unsigned short* __restrict__ k,
    const unsigned short* __restrict__ vt, float* __restrict__ out) {
  __shared__ unsigned short ps[16 * PSTR];
  const int l = threadIdx.x;
  const int mi = l & 15, quad = l >> 4;
  const int bx = blockIdx.x;
  const int qi = 31 - (bx >> 6);  // heavy tiles first
  const int b = bx & 63;

  const unsigned short* qrow = q + ((size_t)b * NT + qi * 16 + mi) * NH;
  bf16x8 qb0 = *(const bf16x8*)(qrow + quad * 8);
  bf16x8 qb1 = *(const bf16x8*)(qrow + 32 + quad * 8);

  f32x4 accO[4];
  const f32x4 zero = {0.f, 0.f, 0.f, 0.f};
#pragma unroll
  for (int i = 0; i < 4; ++i) accO[i] = zero;
  float mrow = -INFINITY, lrow = 0.f;  // per-lane q-row = qi*16 + mi

  const int ktmax = (qi * 16 + 15) >> 6;
  for (int kt = 0; kt <= ktmax; ++kt) {
    const unsigned short* kb = k + ((size_t)b * NT + kt * 64) * NH;
    const unsigned short* vb = vt + (size_t)b * NH * NT + kt * 64;
    bf16x8 ka0[4], ka1[4], va0[4], va1[4];
#pragma unroll
    for (int nt = 0; nt < 4; ++nt) {
      const unsigned short* kr = kb + (size_t)(nt * 16 + mi) * NH + quad * 8;
      ka0[nt] = *(const bf16x8*)kr;
      ka1[nt] = *(const bf16x8*)(kr + 32);
      const unsigned short* vr = vb + (size_t)(nt * 16 + mi) * NT + quad * 8;
      va0[nt] = *(const bf16x8*)vr;
      va1[nt] = *(const bf16x8*)(vr + 32);
    }

    // S^T tile: A = K rows (m=key), B = Q rows (n=q).
    float p[4][4];
#pragma unroll
    for (int nt = 0; nt < 4; ++nt) {
      f32x4 z = zero;
      z = __builtin_amdgcn_mfma_f32_16x16x32_bf16(ka0[nt], qb0, z, 0, 0, 0);
      z = __builtin_amdgcn_mfma_f32_16x16x32_bf16(ka1[nt], qb1, z, 0, 0, 0);
#pragma unroll
      for (int r = 0; r < 4; ++r) p[nt][r] = z[r];
    }

    if (kt == ktmax) {  // causal mask on diagonal tile
#pragma unroll
      for (int nt = 0; nt < 4; ++nt)
#pragma unroll
        for (int r = 0; r < 4; ++r)
          if (kt * 64 + nt * 16 + quad * 4 + r > qi * 16 + mi)
            p[nt][r] = -INFINITY;
    }

    // online softmax for q=mi (keys spread across quads)
    float vmax = -INFINITY;
#pragma unroll
    for (int nt = 0; nt < 4; ++nt)
#pragma unroll
      for (int r = 0; r < 4; ++r) vmax = fmaxf(vmax, p[nt][r]);
    vmax = fmaxf(vmax, __shfl_xor(vmax, 16));
    vmax = fmaxf(vmax, __shfl_xor(vmax, 32));
    float mn = fmaxf(mrow, vmax);
    float alpha = __expf(mrow - mn);
    mrow = mn;

    float rsum = 0.f;
#pragma unroll
    for (int nt = 0; nt < 4; ++nt)
#pragma unroll
      for (int r = 0; r < 4; ++r) {
        p[nt][r] = __expf(p[nt][r] - mn);
        rsum += p[nt][r];
      }
    rsum += __shfl_xor(rsum, 16);
    rsum += __shfl_xor(rsum, 32);
    lrow = lrow * alpha + rsum;

    // P -> LDS (row-contiguous, wave-local, no barrier) -> A-frags
#pragma unroll
    for (int nt = 0; nt < 4; ++nt) {
      uint2 pk;
      pk.x = pk2bf(p[nt][0], p[nt][1]);
      pk.y = pk2bf(p[nt][2], p[nt][3]);
      *(uint2*)&ps[mi * PSTR + nt * 16 + quad * 4] = pk;
    }
    bf16x8 pa0 = *(const bf16x8*)&ps[mi * PSTR + quad * 8];
    bf16x8 pa1 = *(const bf16x8*)&ps[mi * PSTR + 32 + quad * 8];

    float av[4];
#pragma unroll
    for (int r = 0; r < 4; ++r) av[r] = __shfl(alpha, quad * 4 + r);
#pragma unroll
    for (int hi = 0; hi < 4; ++hi)
#pragma unroll
      for (int r = 0; r < 4; ++r) accO[hi][r] *= av[r];

    // O += P V  (A = P rows, B = V^T rows; D col=h, row=q)
#pragma unroll
    for (int hi = 0; hi < 4; ++hi) {
      accO[hi] = __builtin_amdgcn_mfma_f32_16x16x32_bf16(pa0, va0[hi], accO[hi], 0, 0, 0);
      accO[hi] = __builtin_amdgcn_mfma_f32_16x16x32_bf16(pa1, va1[hi], accO[hi], 0, 0, 0);
    }
  }

  // epilogue
  float inv = 1.f / lrow;
  const size_t obase = ((size_t)b * NT + qi * 16) * NH;
#pragma unroll
  for (int r = 0; r < 4; ++r) {
    float iv = __shfl(inv, quad * 4 + r);
#pragma unroll
    for (int hi = 0; hi < 4; ++hi)
      out[obase + (size_t)(quad * 4 + r) * NH + hi * 16 + mi] = accO[hi][r] * iv;
  }
}

extern "C" void kernel_launch(void* const* d_in, const int* in_sizes, int n_in,
                              void* d_out, int out_size, void* d_ws, size_t ws_size,
                              hipStream_t stream) {
  const float* x  = (const float*)d_in[0];
  const float* Wq = (const float*)d_in[1];
  const float* Wk = (const float*)d_in[2];
  const float* Wv = (const float*)d_in[3];

  unsigned short* Wt = (unsigned short*)d_ws;          // 192*384
  unsigned short* qb = Wt + 192 * 384;                 // 32768*64 each
  unsigned short* kb = qb + 32768 * 64;
  unsigned short* vtb = kb + 32768 * 64;               // Vt[b][h][t]
  float* out = (float*)d_out;

  wtrans_kernel<<<288, 256, 0, stream>>>(Wq, Wk, Wv, Wt);
  proj_kernel<<<512, 384, 0, stream>>>(x, Wt, qb, kb, vtb);
  attn_kernel<<<2048, 64, 0, stream>>>(qb, kb, vtb, out);
}